// Round 3
// baseline (616.495 us; speedup 1.0000x reference)
//
#include <hip/hip_runtime.h>
#include <hip/hip_cooperative_groups.h>

namespace cg = cooperative_groups;

// SimpleGraphSAGE: out = mean_agg(x[src]->dst) @ W_l + b_l + x @ W_r
// N=50000, E=640000, IN=128, HID=256.
// R7: fuse memset+prep+hist+scan+permute+agg into ONE cooperative kernel
//     (5 grid.sync()s), phase bodies identical to the verified R6 kernels.
//     Removes ~5 dispatch gaps + memset dispatch; overlaps x/W-prep with
//     hist atomics. gemm_k stays separate (keeps its own occupancy).

constexpr int N_NODES = 50000;
constexpr int N_EDGES = 640000;
constexpr int SCAN_BLOCKS = (N_NODES + 256) / 256;  // 196, covers i==N_NODES
constexpr int GEMM_TILES  = (N_NODES + 63) / 64;    // 782

typedef __attribute__((ext_vector_type(8))) short short8;
typedef __attribute__((ext_vector_type(4))) float f32x4;
typedef _Float16 half8 __attribute__((ext_vector_type(8)));

__device__ inline unsigned short f2h(float f) {
    _Float16 h = (_Float16)f;               // v_cvt_f16_f32, RNE
    return __builtin_bit_cast(unsigned short, h);
}

__device__ inline int block_scan_excl(int v, int tid, int* tmp) {
    tmp[tid] = v;
    __syncthreads();
#pragma unroll
    for (int off = 1; off < 256; off <<= 1) {
        int t = (tid >= off) ? tmp[tid - off] : 0;
        __syncthreads();
        tmp[tid] += t;
        __syncthreads();
    }
    return tmp[tid] - v;
}

// ---------------------------------------------------------------------------
// mega_k: [zero cnt] sync [hist | x->fp16 | W->fp16] sync [scan1] sync
//         [scan23] sync [permute] sync [agg]
// ---------------------------------------------------------------------------
__global__ void mega_k(const float* __restrict__ x,
                       const int* __restrict__ ei,
                       const float* __restrict__ Wl,
                       const float* __restrict__ Wr,
                       unsigned int* __restrict__ Abf_u,
                       unsigned short* __restrict__ Wimg,
                       int* __restrict__ cnt,
                       int* __restrict__ row_start,
                       int* __restrict__ cursor,
                       int* __restrict__ blockSums,
                       int* __restrict__ sorted_src) {
    cg::grid_group grid = cg::this_grid();
    __shared__ int s_tmp[256];
    __shared__ int s_red[256];

    const int tid = threadIdx.x;
    const int bid = blockIdx.x;
    const int nb  = gridDim.x;
    const int gthreads = nb * 256;
    const int gt = bid * 256 + tid;

    // ---- Phase A: zero cnt ----
    for (int i = gt; i < N_NODES; i += gthreads) cnt[i] = 0;
    grid.sync();

    // ---- Phase B: hist + x->fp16 + W->fp16 (independent, co-scheduled) ----
    for (int e = gt; e < N_EDGES; e += gthreads)
        atomicAdd(&cnt[ei[N_EDGES + e]], 1);
    for (int t = gt; t < N_NODES * 32; t += gthreads) {
        float4 v = reinterpret_cast<const float4*>(x)[t];
        unsigned int p0 = (unsigned int)f2h(v.x) | ((unsigned int)f2h(v.y) << 16);
        unsigned int p1 = (unsigned int)f2h(v.z) | ((unsigned int)f2h(v.w) << 16);
        int row = t >> 5, c = t & 31;
        reinterpret_cast<uint2*>(Abf_u)[(size_t)row * 64 + 32 + c] =
            make_uint2(p0, p1);
    }
    for (int t = gt; t < 65536; t += gthreads) {
        int k = t >> 8, n = t & 255;
        float v = (k < 128) ? Wl[k * 256 + n] : Wr[(k - 128) * 256 + n];
        Wimg[(size_t)(k >> 5) * 8192 + n * 32 + (k & 31)] = f2h(v);
    }
    grid.sync();

    // ---- Phase C: scan level 1 ----
    if (bid < SCAN_BLOCKS) {
        int i = bid * 256 + tid;
        int v = (i < N_NODES) ? cnt[i] : 0;
        block_scan_excl(v, tid, s_tmp);
        if (tid == 255) blockSums[bid] = s_tmp[255];
    }
    grid.sync();

    // ---- Phase D: scan levels 2+3 ----
    if (bid < SCAN_BLOCKS) {
        s_red[tid] = (tid < bid) ? blockSums[tid] : 0;
        __syncthreads();
#pragma unroll
        for (int off = 128; off > 0; off >>= 1) {
            if (tid < off) s_red[tid] += s_red[tid + off];
            __syncthreads();
        }
        int boff = s_red[0];
        int i = bid * 256 + tid;
        int v = (i < N_NODES) ? cnt[i] : 0;
        int ex = block_scan_excl(v, tid, s_tmp);
        int rs = boff + ex;
        if (i < N_NODES) {
            row_start[i] = rs;
            cursor[i]    = rs;
        }
        if (i == N_NODES) row_start[N_NODES] = rs;
    }
    grid.sync();

    // ---- Phase E: permute (CSR scatter) ----
    for (int e = gt; e < N_EDGES; e += gthreads) {
        int dst = ei[N_EDGES + e];
        int pos = atomicAdd(&cursor[dst], 1);
        sorted_src[pos] = ei[e];
    }
    grid.sync();

    // ---- Phase F: aggregate (4 nodes/wave, 16 lanes/node, fp16 acc) ----
    {
        const int lane = tid & 63;
        const int g    = lane >> 4;
        const int sub  = lane & 15;
        const int waveId = gt >> 6;
        const int nWaves = gthreads >> 6;
        const half8* X8 = reinterpret_cast<const half8*>(Abf_u);  // row = 32 half8

        for (int unit = waveId; unit < N_NODES / 4; unit += nWaves) {
            int node = unit * 4 + g;
            int beg  = row_start[node];
            int end  = row_start[node + 1];
            int deg  = end - beg;

            half8 acc = {0, 0, 0, 0, 0, 0, 0, 0};

#define LOADV(vj, J)                                                    \
    half8 vj = {0, 0, 0, 0, 0, 0, 0, 0};                                \
    if (base + (J) < deg)                                               \
        vj = X8[(size_t)sorted_src[beg + base + (J)] * 32 + 16 + sub];

            for (int base = 0; base < deg; base += 16) {
                {
                    LOADV(v0, 0) LOADV(v1, 1) LOADV(v2, 2) LOADV(v3, 3)
                    LOADV(v4, 4) LOADV(v5, 5) LOADV(v6, 6) LOADV(v7, 7)
                    acc += ((v0 + v1) + (v2 + v3)) + ((v4 + v5) + (v6 + v7));
                }
                {
                    LOADV(v0, 8)  LOADV(v1, 9)  LOADV(v2, 10) LOADV(v3, 11)
                    LOADV(v4, 12) LOADV(v5, 13) LOADV(v6, 14) LOADV(v7, 15)
                    acc += ((v0 + v1) + (v2 + v3)) + ((v4 + v5) + (v6 + v7));
                }
            }
#undef LOADV

            float inv = (deg > 0) ? 1.0f / (float)deg : 0.0f;
            half8 o;
#pragma unroll
            for (int j = 0; j < 8; j++) o[j] = (_Float16)((float)acc[j] * inv);
            reinterpret_cast<half8*>(Abf_u)[(size_t)node * 32 + sub] = o;
        }
    }
}

// ---------------------------------------------------------------------------
// gemm_k: out[N][256] = Abf[N][256] @ Wcat[256][256] + bl, fp16 MFMA.
// (unchanged from R6)
// ---------------------------------------------------------------------------
__global__ __launch_bounds__(256) void gemm_k(const unsigned short* __restrict__ Abf,
                                              const unsigned short* __restrict__ Wimg,
                                              const float* __restrict__ bl,
                                              float* __restrict__ out) {
    __shared__ unsigned short As[64 * 40];    // rows padded to 40 elems (80B)
    __shared__ unsigned short Bs[256 * 40];

    int tid  = threadIdx.x;
    int w    = tid >> 6;
    int lane = tid & 63;
    int m15  = lane & 15;
    int quad = lane >> 4;
    int bm   = blockIdx.x * 64;

    f32x4 zero4 = {0.f, 0.f, 0.f, 0.f};
    f32x4 acc[4][4];
#pragma unroll
    for (int rt = 0; rt < 4; rt++)
#pragma unroll
        for (int ct = 0; ct < 4; ct++) acc[rt][ct] = zero4;

    for (int kc = 0; kc < 8; kc++) {
        {
            int row = tid >> 2, q = tid & 3;
            int grow = bm + row;
            short8 v = {0, 0, 0, 0, 0, 0, 0, 0};
            if (grow < N_NODES)
                v = *reinterpret_cast<const short8*>(
                        Abf + (size_t)grow * 256 + kc * 32 + q * 8);
            *reinterpret_cast<short8*>(As + row * 40 + q * 8) = v;
        }
        {
            const unsigned short* src = Wimg + (size_t)kc * 8192 + tid * 32;
#pragma unroll
            for (int s = 0; s < 4; s++) {
                short8 v = *reinterpret_cast<const short8*>(src + s * 8);
                *reinterpret_cast<short8*>(Bs + tid * 40 + s * 8) = v;
            }
        }
        __syncthreads();

        half8 Af[4], Bf[4];
#pragma unroll
        for (int rt = 0; rt < 4; rt++)
            Af[rt] = *reinterpret_cast<const half8*>(
                         As + (rt * 16 + m15) * 40 + quad * 8);
#pragma unroll
        for (int ct = 0; ct < 4; ct++)
            Bf[ct] = *reinterpret_cast<const half8*>(
                         Bs + (w * 64 + ct * 16 + m15) * 40 + quad * 8);
#pragma unroll
        for (int rt = 0; rt < 4; rt++)
#pragma unroll
            for (int ct = 0; ct < 4; ct++)
                acc[rt][ct] = __builtin_amdgcn_mfma_f32_16x16x32_f16(
                    Af[rt], Bf[ct], acc[rt][ct], 0, 0, 0);
        __syncthreads();
    }

    float bias[4];
#pragma unroll
    for (int ct = 0; ct < 4; ct++) bias[ct] = bl[w * 64 + ct * 16 + m15];
#pragma unroll
    for (int rt = 0; rt < 4; rt++) {
        int rb = bm + rt * 16 + quad * 4;
#pragma unroll
        for (int r = 0; r < 4; r++) {
            int row = rb + r;
            if (row < N_NODES) {
#pragma unroll
                for (int ct = 0; ct < 4; ct++)
                    out[(size_t)row * 256 + w * 64 + ct * 16 + m15] =
                        acc[rt][ct][r] + bias[ct];
            }
        }
    }
}

extern "C" void kernel_launch(void* const* d_in, const int* in_sizes, int n_in,
                              void* d_out, int out_size, void* d_ws, size_t ws_size,
                              hipStream_t stream) {
    const float* x  = (const float*)d_in[0];
    const int*   ei = (const int*)d_in[1];   // [2, E] int32
    const float* Wl = (const float*)d_in[2];
    const float* bl = (const float*)d_in[3];
    const float* Wr = (const float*)d_in[4];
    float* out = (float*)d_out;

    // ws layout
    unsigned short* Abf  = (unsigned short*)d_ws;              // N*256 fp16
    unsigned short* Wimg = Abf + (size_t)N_NODES * 256;        // 65536 fp16
    int* cnt        = (int*)(Wimg + 65536);                    // N
    int* row_start  = cnt + N_NODES;                           // N+1
    int* cursor     = row_start + N_NODES + 1;                 // N
    int* blockSums  = cursor + N_NODES;                        // 256
    int* sorted_src = blockSums + 256;                         // E

    unsigned int* Abf_u = (unsigned int*)Abf;

    // Cooperative grid: sized once from the occupancy query (co-residency
    // required for grid.sync). Cap 1024 blocks: 4096 waves -> agg does
    // 12500/4096 = 3.05 balanced rounds; scan needs >=196 blocks.
    static int G = 0;
    if (G == 0) {
        int maxB = 0;
        if (hipOccupancyMaxActiveBlocksPerMultiprocessor(&maxB, mega_k, 256, 0)
                != hipSuccess || maxB < 1)
            maxB = 2;
        long g = (long)maxB * 256;   // 256 CUs on MI355X
        G = (int)(g < 1024 ? g : 1024);
        if (G < 256) G = 256;
    }

    void* args[] = {(void*)&x, (void*)&ei, (void*)&Wl, (void*)&Wr,
                    (void*)&Abf_u, (void*)&Wimg, (void*)&cnt, (void*)&row_start,
                    (void*)&cursor, (void*)&blockSums, (void*)&sorted_src};
    hipLaunchCooperativeKernel(mega_k, dim3(G), dim3(256), args, 0u, stream);

    gemm_k<<<GEMM_TILES, 256, 0, stream>>>(Abf, Wimg, bl, out);
}

// Round 4
// 229.339 us; speedup vs baseline: 2.6881x; 2.6881x over previous
//
#include <hip/hip_runtime.h>

// SimpleGraphSAGE: out = mean_agg(x[src]->dst) @ W_l + b_l + x @ W_r
// N=50000, E=640000, IN=128, HID=256.
// R8: revert R7's cooperative fusion (grid.sync ~100us/barrier on 8-XCD —
//     622us total). Back to the R6 dispatch chain, but fuse agg INTO gemm:
//     each 64-row gemm block mean-aggregates its own nodes into the LDS
//     A-tile (16 lanes/node, 8 gather chains in flight), then runs MFMA.
//     X table shrinks to dense [N][128] fp16. Removes agg dispatch + 19MB
//     of Abf mean traffic; gather overlaps MFMA across blocks on a CU.

constexpr int N_NODES = 50000;
constexpr int N_EDGES = 640000;
constexpr int SCAN_BLOCKS = (N_NODES + 256) / 256;  // 196, covers i==N_NODES
constexpr int GEMM_TILES  = (N_NODES + 63) / 64;    // 782

constexpr int HIST_BLOCKS  = N_EDGES / 1024;        // 625, thread handles 4 edges
constexpr int PREPX_BLOCKS = N_NODES * 32 / 256;    // 6250, thread = 4 channels
constexpr int WPREP_BLOCKS = 256;                   // 65536 weight elems

typedef __attribute__((ext_vector_type(8))) short short8;
typedef __attribute__((ext_vector_type(4))) float f32x4;
typedef _Float16 half8 __attribute__((ext_vector_type(8)));

__device__ inline unsigned short f2h(float f) {
    _Float16 h = (_Float16)f;               // v_cvt_f16_f32, RNE
    return __builtin_bit_cast(unsigned short, h);
}

// ---------------------------------------------------------------------------
// prep_k: block-range fused  [hist | x->fp16 | W->fp16 tiled]
// x image is now dense [N][128] fp16 (row = 32 uint2), write fully linear.
// ---------------------------------------------------------------------------
__global__ __launch_bounds__(256) void prep_k(const float* __restrict__ x,
                                              const int* __restrict__ ei,
                                              const float* __restrict__ Wl,
                                              const float* __restrict__ Wr,
                                              unsigned int* __restrict__ Xu,
                                              unsigned short* __restrict__ Wimg,
                                              int* __restrict__ cnt) {
    int bid = blockIdx.x, tid = threadIdx.x;
    if (bid < HIST_BLOCKS) {
        int base = bid * 1024 + tid;
#pragma unroll
        for (int k = 0; k < 4; k++)
            atomicAdd(&cnt[ei[N_EDGES + base + k * 256]], 1);
    } else if (bid < HIST_BLOCKS + PREPX_BLOCKS) {
        int t = (bid - HIST_BLOCKS) * 256 + tid;          // < N*32
        float4 v = reinterpret_cast<const float4*>(x)[t];
        unsigned int p0 = (unsigned int)f2h(v.x) | ((unsigned int)f2h(v.y) << 16);
        unsigned int p1 = (unsigned int)f2h(v.z) | ((unsigned int)f2h(v.w) << 16);
        reinterpret_cast<uint2*>(Xu)[t] = make_uint2(p0, p1);
    } else {
        int t = (bid - HIST_BLOCKS - PREPX_BLOCKS) * 256 + tid;  // < 65536
        int k = t >> 8, n = t & 255;
        float v = (k < 128) ? Wl[k * 256 + n] : Wr[(k - 128) * 256 + n];
        Wimg[(size_t)(k >> 5) * 8192 + n * 32 + (k & 31)] = f2h(v);
    }
}

// ---------------------------------------------------------------------------
// CSR build: scan + permute (unchanged from R6)
// ---------------------------------------------------------------------------
__device__ inline int block_scan_excl(int v, int tid, int* tmp) {
    tmp[tid] = v;
    __syncthreads();
#pragma unroll
    for (int off = 1; off < 256; off <<= 1) {
        int t = (tid >= off) ? tmp[tid - off] : 0;
        __syncthreads();
        tmp[tid] += t;
        __syncthreads();
    }
    return tmp[tid] - v;
}

__global__ __launch_bounds__(256) void scan1_k(const int* __restrict__ cnt,
                                               int* __restrict__ blockSums) {
    __shared__ int tmp[256];
    int i = blockIdx.x * 256 + threadIdx.x;
    int v = (i < N_NODES) ? cnt[i] : 0;
    block_scan_excl(v, threadIdx.x, tmp);
    if (threadIdx.x == 255) blockSums[blockIdx.x] = tmp[255];
}

__global__ __launch_bounds__(256) void scan23_k(const int* __restrict__ cnt,
                                                const int* __restrict__ blockSums,
                                                int* __restrict__ row_start,
                                                int* __restrict__ cursor) {
    __shared__ int red[256];
    __shared__ int tmp[256];
    int tid = threadIdx.x;
    int bv = (tid < (int)blockIdx.x) ? blockSums[tid] : 0;  // blockIdx < 256
    red[tid] = bv;
    __syncthreads();
#pragma unroll
    for (int off = 128; off > 0; off >>= 1) {
        if (tid < off) red[tid] += red[tid + off];
        __syncthreads();
    }
    int boff = red[0];
    int i = blockIdx.x * 256 + tid;
    int v = (i < N_NODES) ? cnt[i] : 0;
    int ex = block_scan_excl(v, tid, tmp);
    int rs = boff + ex;
    if (i < N_NODES) {
        row_start[i] = rs;
        cursor[i]    = rs;
    }
    if (i == N_NODES) row_start[N_NODES] = rs;
}

__global__ __launch_bounds__(256) void permute_k(const int* __restrict__ ei,
                                                 int* __restrict__ cursor,
                                                 int* __restrict__ sorted_src) {
    int e = blockIdx.x * 256 + threadIdx.x;
    if (e >= N_EDGES) return;
    int dst = ei[N_EDGES + e];
    int pos = atomicAdd(&cursor[dst], 1);
    sorted_src[pos] = ei[e];
}

// ---------------------------------------------------------------------------
// gemm_k (R8, fused agg+GEMM): block owns 64 output rows.
// Phase 1: 4 waves aggregate the 64 nodes (16 lanes per node, g=node-in-
//   group, sub=16B chunk; 8 predicated gather chains in flight), fp16 tree
//   accumulate, mean written as half8 into the LDS A-tile chunks (kc 0..3).
// Phase 2: standard MFMA loop; kc<4 reads means from As4, kc>=4 stages the
//   x columns from the dense Xf image.
// LDS = 4*5KB (means) + 5KB (x chunk) + 20KB (B) = 45KB -> 3 blocks/CU.
// ---------------------------------------------------------------------------
__global__ __launch_bounds__(256) void gemm_k(const unsigned short* __restrict__ Xf,
                                              const int* __restrict__ row_start,
                                              const int* __restrict__ sorted_src,
                                              const unsigned short* __restrict__ Wimg,
                                              const float* __restrict__ bl,
                                              float* __restrict__ out) {
    __shared__ unsigned short As4[4 * 64 * 40];  // mean chunks kc=0..3, stride 40
    __shared__ unsigned short AsX[64 * 40];      // x chunk staging (kc=4..7)
    __shared__ unsigned short Bs[256 * 40];

    int tid  = threadIdx.x;
    int w    = tid >> 6;
    int lane = tid & 63;
    int m15  = lane & 15;   // also `sub` in phase 1
    int quad = lane >> 4;   // also `g` in phase 1
    int bm   = blockIdx.x * 64;

    const half8* X8 = reinterpret_cast<const half8*>(Xf);  // row = 16 half8

    // ---- Phase 1: aggregate means into As4 ----
#pragma unroll 1
    for (int r4 = 0; r4 < 4; r4++) {
        int nl   = w * 16 + r4 * 4 + quad;   // 0..63, unique per (w,r4,g)
        int node = bm + nl;
        int beg = 0, deg = 0;
        if (node < N_NODES) {
            beg = row_start[node];
            deg = row_start[node + 1] - beg;
        }
        half8 acc = {0, 0, 0, 0, 0, 0, 0, 0};

#define LOADV(vj, J)                                                    \
    half8 vj = {0, 0, 0, 0, 0, 0, 0, 0};                                \
    if (base + (J) < deg)                                               \
        vj = X8[(size_t)sorted_src[beg + base + (J)] * 16 + m15];

        for (int base = 0; base < deg; base += 16) {
            {
                LOADV(v0, 0) LOADV(v1, 1) LOADV(v2, 2) LOADV(v3, 3)
                LOADV(v4, 4) LOADV(v5, 5) LOADV(v6, 6) LOADV(v7, 7)
                acc += ((v0 + v1) + (v2 + v3)) + ((v4 + v5) + (v6 + v7));
            }
            {
                LOADV(v0, 8)  LOADV(v1, 9)  LOADV(v2, 10) LOADV(v3, 11)
                LOADV(v4, 12) LOADV(v5, 13) LOADV(v6, 14) LOADV(v7, 15)
                acc += ((v0 + v1) + (v2 + v3)) + ((v4 + v5) + (v6 + v7));
            }
        }
#undef LOADV

        float inv = (deg > 0) ? 1.0f / (float)deg : 0.0f;
        half8 o;
#pragma unroll
        for (int j = 0; j < 8; j++) o[j] = (_Float16)((float)acc[j] * inv);
        // col range of this lane: m15*8 .. m15*8+7  -> chunk = m15>>2, q = m15&3
        *reinterpret_cast<half8*>(
            &As4[(m15 >> 2) * 2560 + nl * 40 + (m15 & 3) * 8]) = o;
    }
    // As4 writes are made visible by the first __syncthreads in the kc loop.

    // ---- Phase 2: MFMA loop ----
    f32x4 zero4 = {0.f, 0.f, 0.f, 0.f};
    f32x4 acc[4][4];
#pragma unroll
    for (int rt = 0; rt < 4; rt++)
#pragma unroll
        for (int ct = 0; ct < 4; ct++) acc[rt][ct] = zero4;

    for (int kc = 0; kc < 8; kc++) {
        if (kc >= 4) {
            int row = tid >> 2, q = tid & 3;
            int grow = bm + row;
            short8 v = {0, 0, 0, 0, 0, 0, 0, 0};
            if (grow < N_NODES)
                v = *reinterpret_cast<const short8*>(
                        Xf + (size_t)grow * 128 + (kc - 4) * 32 + q * 8);
            *reinterpret_cast<short8*>(AsX + row * 40 + q * 8) = v;
        }
        {
            const unsigned short* src = Wimg + (size_t)kc * 8192 + tid * 32;
#pragma unroll
            for (int s = 0; s < 4; s++) {
                short8 v = *reinterpret_cast<const short8*>(src + s * 8);
                *reinterpret_cast<short8*>(Bs + tid * 40 + s * 8) = v;
            }
        }
        __syncthreads();

        const unsigned short* Ach = (kc < 4) ? &As4[kc * 2560] : AsX;
        half8 Af[4], Bf[4];
#pragma unroll
        for (int rt = 0; rt < 4; rt++)
            Af[rt] = *reinterpret_cast<const half8*>(
                         Ach + (rt * 16 + m15) * 40 + quad * 8);
#pragma unroll
        for (int ct = 0; ct < 4; ct++)
            Bf[ct] = *reinterpret_cast<const half8*>(
                         Bs + (w * 64 + ct * 16 + m15) * 40 + quad * 8);
#pragma unroll
        for (int rt = 0; rt < 4; rt++)
#pragma unroll
            for (int ct = 0; ct < 4; ct++)
                acc[rt][ct] = __builtin_amdgcn_mfma_f32_16x16x32_f16(
                    Af[rt], Bf[ct], acc[rt][ct], 0, 0, 0);
        __syncthreads();
    }

    float bias[4];
#pragma unroll
    for (int ct = 0; ct < 4; ct++) bias[ct] = bl[w * 64 + ct * 16 + m15];
#pragma unroll
    for (int rt = 0; rt < 4; rt++) {
        int rb = bm + rt * 16 + quad * 4;
#pragma unroll
        for (int r = 0; r < 4; r++) {
            int row = rb + r;
            if (row < N_NODES) {
#pragma unroll
                for (int ct = 0; ct < 4; ct++)
                    out[(size_t)row * 256 + w * 64 + ct * 16 + m15] =
                        acc[rt][ct][r] + bias[ct];
            }
        }
    }
}

extern "C" void kernel_launch(void* const* d_in, const int* in_sizes, int n_in,
                              void* d_out, int out_size, void* d_ws, size_t ws_size,
                              hipStream_t stream) {
    const float* x  = (const float*)d_in[0];
    const int*   ei = (const int*)d_in[1];   // [2, E] int32
    const float* Wl = (const float*)d_in[2];
    const float* bl = (const float*)d_in[3];
    const float* Wr = (const float*)d_in[4];
    float* out = (float*)d_out;

    // ws layout
    unsigned short* Xf   = (unsigned short*)d_ws;              // N*128 fp16
    unsigned short* Wimg = Xf + (size_t)N_NODES * 128;         // 65536 fp16
    int* cnt        = (int*)(Wimg + 65536);                    // N
    int* row_start  = cnt + N_NODES;                           // N+1
    int* cursor     = row_start + N_NODES + 1;                 // N
    int* blockSums  = cursor + N_NODES;                        // 256
    int* sorted_src = blockSums + 256;                         // E

    hipMemsetAsync(cnt, 0, N_NODES * sizeof(int), stream);

    prep_k<<<HIST_BLOCKS + PREPX_BLOCKS + WPREP_BLOCKS, 256, 0, stream>>>(
        x, ei, Wl, Wr, (unsigned int*)Xf, Wimg, cnt);
    scan1_k<<<SCAN_BLOCKS, 256, 0, stream>>>(cnt, blockSums);
    scan23_k<<<SCAN_BLOCKS, 256, 0, stream>>>(cnt, blockSums, row_start, cursor);
    permute_k<<<(N_EDGES + 255) / 256, 256, 0, stream>>>(ei, cursor, sorted_src);
    gemm_k<<<GEMM_TILES, 256, 0, stream>>>(Xf, row_start, sorted_src, Wimg, bl,
                                           out);
}